// Round 9
// baseline (127.105 us; speedup 1.0000x reference)
//
#include <hip/hip_runtime.h>
#include <math.h>
#include <float.h>

#define EPS 1e-6f
#define THRESHOLD 0.5f

#define NB 16
#define NPOLY 16
#define NVERT 200
#define NSEG_PER_POLY 199
#define NSEG_REAL (NPOLY * NSEG_PER_POLY)  // 3184 real segments per batch
#define NPTB 300                           // points per batch (10 agents * 30)
#define NPOINTS 4800                       // 16 * 300
#define NSLICE 64
#define SEG_PER_SLICE 50                   // COMPILE-TIME trip count (padded)

// ---------------------------------------------------------------------------
// Two-kernel structure (R7 skeleton = best @79.6; R8's s_load table regressed).
// R9 change: constant trip count (slice 63 padded with inert segments in the
// prologue) + full unroll, so the compiler can software-pipeline the
// ds_read_b128 pairs across iterations — R7's runtime-variable `nseg` blocked
// that, leaving the loop LDS-latency-bound (VALU slimming R6->R7 bought only
// 2 us; that was the tell).
//
// seg_kernel: one block per (batch, slice).
//  Prologue : lanes 0..49 precompute segment -> LDS (divides/rcp hoisted);
//             pad entries (s >= 3184) are inert: dsq=+inf (never min),
//             cond_y always false (never crosses, never hits fallback).
//  Main loop: lane = point; wave-uniform broadcast ds_read_b128; dual
//             accumulators; distance path ulp-tolerant (fma/med3);
//             crossing = rcp fast path + per-lane EXACT IEEE-div fallback
//             (bit-matches numpy; absmax has been 0.0 for 5 rounds).
//  Epilogue : float2{min_dsq, crossings} partials; slice-0 idle lanes
//             (lp 300..309) zero out[] (poisoned 0xAA).
// ---------------------------------------------------------------------------
__global__ __launch_bounds__(320) void seg_kernel(
    const float* __restrict__ points,
    const float* __restrict__ polys,
    float2* __restrict__ part,        // [NSLICE][NPOINTS]
    float* __restrict__ out)
{
    __shared__ float4 lds[SEG_PER_SLICE * 2];

    const int slice = blockIdx.x;       // 0..63
    const int b     = blockIdx.y;       // 0..15
    const int lp    = threadIdx.x;      // 0..319; points 0..299 valid
    const bool active = lp < NPTB;

    // ---- prologue: per-segment precompute into LDS (padded to 50) ----
    if (lp < SEG_PER_SLICE) {
        const int s = slice * SEG_PER_SLICE + lp;
        float4 e0, e1;
        if (s < NSEG_REAL) {
            const int m = s / NSEG_PER_POLY;
            const int v = s % NSEG_PER_POLY;
            const float2* poly = (const float2*)polys + ((size_t)(b * NPOLY + m) * NVERT);
            const float2 S = poly[v];
            const float2 E = poly[v + 1];
            const float evx = E.x - S.x;
            const float evy = E.y - S.y;
            const float esq = evx * evx + evy * evy;
            const float inv_esq = 1.0f / (esq + EPS);
            const float slope_eps = evy / (evx + EPS) + EPS;  // exact IEEE, ref order
            const float inv_slope = __builtin_amdgcn_rcpf(slope_eps);
            e0 = make_float4(S.x, S.y, evx, evy);
            e1 = make_float4(inv_esq, slope_eps, inv_slope, E.y);
        } else {
            // inert: dsq=+inf, cond_y=false, no fallback
            e0 = make_float4(1e30f, 1e30f, 0.0f, 0.0f);
            e1 = make_float4(0.0f, 1.0f, 1.0f, 1e30f);
        }
        lds[lp * 2]     = e0;
        lds[lp * 2 + 1] = e1;
    }
    __syncthreads();

    const int pidx = b * NPTB + (active ? lp : 0);
    const float2 pt = *(const float2*)(points + (size_t)pidx * 2);
    const float px = pt.x, py = pt.y;

    float min_a = FLT_MAX, min_b = FLT_MAX;
    int cr_a = 0, cr_b = 0;

    auto body = [&](int j, float& mn, int& cr) {
        const float4 p0 = lds[j * 2];       // wave-uniform -> broadcast
        const float4 p1 = lds[j * 2 + 1];
        const float sx = p0.x, sy = p0.y, evx = p0.z, evy = p0.w;
        const float inv_esq = p1.x, slope_eps = p1.y, inv_slope = p1.z, ey = p1.w;

        // ---- point-to-segment squared distance (ulp-tolerant path) ----
        const float v1x = px - sx;
        const float v1y = py - sy;
        const float dot = fmaf(v1y, evy, v1x * evx);
        const float t   = __builtin_amdgcn_fmed3f(dot * inv_esq, 0.0f, 1.0f);
        const float dx  = fmaf(-evx, t, v1x);
        const float dy  = fmaf(-evy, t, v1y);
        const float dsq = fmaf(dy, dy, dx * dx);
        mn = fminf(mn, dsq);

        // ---- even-odd crossing: rcp fast path + exact-div fallback ----
        const bool cond_y = (sy <= py) != (ey <= py);   // == ref's cond_y, exact
        const float q    = v1y * inv_slope;             // ~3 ulp
        const float ixa  = sx + q;
        const float diff = ixa - px;
        const float err  = fmaf(fabsf(q) + fabsf(ixa), 1e-6f, 1e-30f);
        bool left = diff > 0.0f;
        if (cond_y && !(fabsf(diff) > err)) {
            // rare: decision within rcp noise — replicate ref bit-exactly
            left = (sx + v1y / slope_eps) > px;
        }
        cr += (cond_y && left) ? 1 : 0;
    };

    // compile-time trip count + full unroll -> compiler pipelines ds_reads
    #pragma unroll
    for (int j = 0; j < SEG_PER_SLICE; j += 2) {
        body(j,     min_a, cr_a);
        body(j + 1, min_b, cr_b);
    }

    if (active) {
        part[slice * NPOINTS + pidx] =
            make_float2(fminf(min_a, min_b), __int_as_float(cr_a + cr_b));
    } else if (slice == 0 && lp >= NPTB && lp < NPTB + 10) {
        // zero out[] (poisoned 0xAA); final_kernel atomics run after seg
        // completes (stream order) — race-free.
        out[b * 10 + (lp - NPTB)] = 0.0f;
    }
}

// ---------------------------------------------------------------------------
// Per-point reduction over 64 slices + epilogue + atomic into out.
// ---------------------------------------------------------------------------
__global__ __launch_bounds__(256) void final_kernel(
    const float2* __restrict__ part,
    float* __restrict__ out)
{
    const int p = blockIdx.x * 256 + threadIdx.x;
    if (p >= NPOINTS) return;

    float md = FLT_MAX;
    int c = 0;
    #pragma unroll 8
    for (int k = 0; k < NSLICE; ++k) {
        const float2 pr = part[k * NPOINTS + p];
        md = fminf(md, pr.x);
        c += __float_as_int(pr.y);
    }

    float d = sqrtf(fmaxf(md, EPS));
    if (c & 1) d = -d;
    const float val = fmaxf(d + THRESHOLD, 0.0f);

    const int b = p / NPTB;
    const int a = (p % NPTB) / 30;
    atomicAdd(out + b * 10 + a, val);
}

extern "C" void kernel_launch(void* const* d_in, const int* in_sizes, int n_in,
                              void* d_out, int out_size, void* d_ws, size_t ws_size,
                              hipStream_t stream) {
    const float* points = (const float*)d_in[0];   // (16,10,30,2)
    const float* polys  = (const float*)d_in[1];   // (16,16,200,2)
    float* out = (float*)d_out;                    // (16,10)

    float2* part = (float2*)d_ws;                  // 64*4800*8 B = 2.4 MB

    dim3 grid(NSLICE, NB);                         // 64 x 16 = 1024 blocks
    seg_kernel<<<grid, 320, 0, stream>>>(points, polys, part, out);
    final_kernel<<<(NPOINTS + 255) / 256, 256, 0, stream>>>(part, out);
}

// Round 10
// 80.695 us; speedup vs baseline: 1.5751x; 1.5751x over previous
//
#include <hip/hip_runtime.h>
#include <math.h>
#include <float.h>

#define EPS 1e-6f
#define THRESHOLD 0.5f

#define NB 16
#define NPOLY 16
#define NVERT 200
#define NSEG_PER_POLY 199
#define NSEG_REAL (NPOLY * NSEG_PER_POLY)  // 3184 real segments per batch
#define NPTB 300                           // points per batch (10 agents * 30)
#define NPOINTS 4800                       // 16 * 300
#define NSLICE 64
#define SEG_PER_SLICE 50                   // compile-time trip count (padded)
#define LDS_ENTRIES (SEG_PER_SLICE + 2)    // +2 so the pipeline preload at
                                           // j=48 reads inert entries 50,51

// ---------------------------------------------------------------------------
// R10: R7 skeleton (best @79.6) + MANUAL 2-stage software pipeline.
// R9 post-mortem: full unroll hoisted ~100 float4 LDS loads -> VGPR 128,
// 115 MB scratch spill traffic, 127 us. Fix: rotate-register pipeline of
// depth 2 with `#pragma unroll 1` (pinned rolled) — preload pair j+2/j+3
// while computing pair j/j+1. Live pipeline regs = 8 x float4 = 32 VGPRs.
//
// seg_kernel: one block per (batch, slice).
//  Prologue : lanes 0..51 precompute segment -> LDS (divides/rcp hoisted);
//             pad entries (s >= 3184 or lp >= 50) are inert: dsq=+inf
//             (never the min), cond_y=false (no crossing, no fallback).
//  Main loop: lane = point; wave-uniform broadcast ds_read_b128; dual
//             accumulators; distance path ulp-tolerant (fma/med3);
//             crossing = rcp fast path + per-lane EXACT IEEE-div fallback
//             (bit-matches numpy; absmax 0.0 since R1).
//  Epilogue : float2{min_dsq, crossings} partials; slice-0 idle lanes
//             (lp 300..309) zero out[] (poisoned 0xAA).
// ---------------------------------------------------------------------------
__global__ __launch_bounds__(320) void seg_kernel(
    const float* __restrict__ points,
    const float* __restrict__ polys,
    float2* __restrict__ part,        // [NSLICE][NPOINTS]
    float* __restrict__ out)
{
    __shared__ float4 lds[LDS_ENTRIES * 2];

    const int slice = blockIdx.x;       // 0..63
    const int b     = blockIdx.y;       // 0..15
    const int lp    = threadIdx.x;      // 0..319; points 0..299 valid
    const bool active = lp < NPTB;

    // ---- prologue: per-segment precompute into LDS (padded to 52) ----
    if (lp < LDS_ENTRIES) {
        const int s = slice * SEG_PER_SLICE + lp;
        float4 e0, e1;
        if (lp < SEG_PER_SLICE && s < NSEG_REAL) {
            const int m = s / NSEG_PER_POLY;
            const int v = s % NSEG_PER_POLY;
            const float2* poly = (const float2*)polys + ((size_t)(b * NPOLY + m) * NVERT);
            const float2 S = poly[v];
            const float2 E = poly[v + 1];
            const float evx = E.x - S.x;
            const float evy = E.y - S.y;
            const float esq = evx * evx + evy * evy;
            const float inv_esq = 1.0f / (esq + EPS);
            const float slope_eps = evy / (evx + EPS) + EPS;  // exact IEEE, ref order
            const float inv_slope = __builtin_amdgcn_rcpf(slope_eps);
            e0 = make_float4(S.x, S.y, evx, evy);
            e1 = make_float4(inv_esq, slope_eps, inv_slope, E.y);
        } else {
            // inert: dsq=+inf, cond_y=false, no fallback
            e0 = make_float4(1e30f, 1e30f, 0.0f, 0.0f);
            e1 = make_float4(0.0f, 1.0f, 1.0f, 1e30f);
        }
        lds[lp * 2]     = e0;
        lds[lp * 2 + 1] = e1;
    }
    __syncthreads();

    const int pidx = b * NPTB + (active ? lp : 0);
    const float2 pt = *(const float2*)(points + (size_t)pidx * 2);
    const float px = pt.x, py = pt.y;

    float min_a = FLT_MAX, min_b = FLT_MAX;
    int cr_a = 0, cr_b = 0;

    auto body = [&](const float4& p0, const float4& p1, float& mn, int& cr) {
        const float sx = p0.x, sy = p0.y, evx = p0.z, evy = p0.w;
        const float inv_esq = p1.x, slope_eps = p1.y, inv_slope = p1.z, ey = p1.w;

        // ---- point-to-segment squared distance (ulp-tolerant path) ----
        const float v1x = px - sx;
        const float v1y = py - sy;
        const float dot = fmaf(v1y, evy, v1x * evx);
        const float t   = __builtin_amdgcn_fmed3f(dot * inv_esq, 0.0f, 1.0f);
        const float dx  = fmaf(-evx, t, v1x);
        const float dy  = fmaf(-evy, t, v1y);
        const float dsq = fmaf(dy, dy, dx * dx);
        mn = fminf(mn, dsq);

        // ---- even-odd crossing: rcp fast path + exact-div fallback ----
        const bool cond_y = (sy <= py) != (ey <= py);   // == ref's cond_y, exact
        const float q    = v1y * inv_slope;             // ~3 ulp
        const float ixa  = sx + q;
        const float diff = ixa - px;
        const float err  = fmaf(fabsf(q) + fabsf(ixa), 1e-6f, 1e-30f);
        bool left = diff > 0.0f;
        if (cond_y && !(fabsf(diff) > err)) {
            // rare: decision within rcp noise — replicate ref bit-exactly
            left = (sx + v1y / slope_eps) > px;
        }
        cr += (cond_y && left) ? 1 : 0;
    };

    // ---- manual 2-stage software pipeline over LDS ----
    float4 a0 = lds[0], a1 = lds[1];     // pair j
    float4 b0 = lds[2], b1 = lds[3];     // pair j+1
    #pragma unroll 1
    for (int j = 0; j < SEG_PER_SLICE; j += 2) {
        // preload pair j+2 / j+3 (inert pad at 50,51 keeps this in-bounds)
        const float4 n0 = lds[(j + 2) * 2],     n1 = lds[(j + 2) * 2 + 1];
        const float4 m0 = lds[(j + 3) * 2],     m1 = lds[(j + 3) * 2 + 1];
        body(a0, a1, min_a, cr_a);
        body(b0, b1, min_b, cr_b);
        a0 = n0; a1 = n1; b0 = m0; b1 = m1;
    }

    if (active) {
        part[slice * NPOINTS + pidx] =
            make_float2(fminf(min_a, min_b), __int_as_float(cr_a + cr_b));
    } else if (slice == 0 && lp >= NPTB && lp < NPTB + 10) {
        // zero out[] (poisoned 0xAA); final_kernel atomics run after seg
        // completes (stream order) — race-free.
        out[b * 10 + (lp - NPTB)] = 0.0f;
    }
}

// ---------------------------------------------------------------------------
// Per-point reduction over 64 slices + epilogue + atomic into out.
// ---------------------------------------------------------------------------
__global__ __launch_bounds__(256) void final_kernel(
    const float2* __restrict__ part,
    float* __restrict__ out)
{
    const int p = blockIdx.x * 256 + threadIdx.x;
    if (p >= NPOINTS) return;

    float md = FLT_MAX;
    int c = 0;
    #pragma unroll 8
    for (int k = 0; k < NSLICE; ++k) {
        const float2 pr = part[k * NPOINTS + p];
        md = fminf(md, pr.x);
        c += __float_as_int(pr.y);
    }

    float d = sqrtf(fmaxf(md, EPS));
    if (c & 1) d = -d;
    const float val = fmaxf(d + THRESHOLD, 0.0f);

    const int b = p / NPTB;
    const int a = (p % NPTB) / 30;
    atomicAdd(out + b * 10 + a, val);
}

extern "C" void kernel_launch(void* const* d_in, const int* in_sizes, int n_in,
                              void* d_out, int out_size, void* d_ws, size_t ws_size,
                              hipStream_t stream) {
    const float* points = (const float*)d_in[0];   // (16,10,30,2)
    const float* polys  = (const float*)d_in[1];   // (16,16,200,2)
    float* out = (float*)d_out;                    // (16,10)

    float2* part = (float2*)d_ws;                  // 64*4800*8 B = 2.4 MB

    dim3 grid(NSLICE, NB);                         // 64 x 16 = 1024 blocks
    seg_kernel<<<grid, 320, 0, stream>>>(points, polys, part, out);
    final_kernel<<<(NPOINTS + 255) / 256, 256, 0, stream>>>(part, out);
}